// Round 2
// baseline (163.211 us; speedup 1.0000x reference)
//
#include <hip/hip_runtime.h>

// SSD300 post-process: argmax over 21 class confidences, validity mask,
// and offset->box decode. Memory-bound (~139 MB moved -> ~22 us floor).
//
// Layout decisions:
//  - block = 256 threads handles 256 consecutive anchors of ONE batch image.
//  - confidences for the chunk (256*21 floats = 21.5 KB) staged to LDS with
//    coalesced float4 loads (chunk base provably 16B-aligned since
//    256*21*4 B and 8732*21*4 B are multiples of 16).
//  - per-thread LDS read stride = 21 floats (odd) -> bank permutation,
//    2 lanes/bank for wave64 = conflict-free.
//  - offsets / default_boxes / boxes are natural float4 per anchor.
// Output buffer is flat f32: [boxes B*N*4][pred_cls B*N][valid B*N].

constexpr int kB    = 128;
constexpr int kNBox = 8732;
constexpr int kNCls = 21;
constexpr int kChunk = 256;
constexpr float kConfThresh = 0.05f;

__global__ __launch_bounds__(kChunk) void ssd_decode_kernel(
    const float* __restrict__ offsets,   // [B, N, 4]
    const float* __restrict__ conf,      // [B, N, 21]
    const float* __restrict__ dboxes,    // [N, 4]
    float* __restrict__ out)             // [B*N*4 | B*N | B*N]
{
    __shared__ __align__(16) float s_conf[kChunk * kNCls];  // 21504 B

    const int b   = blockIdx.y;
    const int n0  = blockIdx.x * kChunk;
    const int cnt = min(kChunk, kNBox - n0);
    const int tid = threadIdx.x;

    // ---- stage confidences chunk into LDS (coalesced float4) ----
    const size_t coff = ((size_t)b * kNBox + n0) * kNCls;
    const int nflt = cnt * kNCls;          // 5376 (full) or 588 (tail chunk)
    const int nv4  = nflt >> 2;            // both cases divisible by 4
    const float4* __restrict__ c4 = reinterpret_cast<const float4*>(conf + coff);
    float4* s4 = reinterpret_cast<float4*>(s_conf);
    for (int i = tid; i < nv4; i += kChunk) {
        s4[i] = c4[i];
    }
    // generic tail guard (no-op for this problem's shapes)
    for (int i = (nv4 << 2) + tid; i < nflt; i += kChunk) {
        s_conf[i] = conf[coff + i];
    }
    __syncthreads();

    if (tid < cnt) {
        const int n = n0 + tid;

        // ---- argmax over 21 classes (first-occurrence on ties) ----
        const float* c = s_conf + tid * kNCls;
        float best = c[0];
        int cls = 0;
        #pragma unroll
        for (int k = 1; k < kNCls; ++k) {
            const float v = c[k];
            if (v > best) { best = v; cls = k; }
        }
        const bool valid = (cls != 0) && (best > kConfThresh);

        // ---- box decode ----
        const size_t an = (size_t)b * kNBox + n;
        const float4 off = reinterpret_cast<const float4*>(offsets)[an];
        const float4 d   = reinterpret_cast<const float4*>(dboxes)[n];
        const float cx = d.x + off.x * d.z;
        const float cy = d.y + off.y * d.w;
        const float w  = d.z * expf(off.z);
        const float h  = d.w * expf(off.w);

        float4 box;
        if (valid) {
            box.x = cx - 0.5f * w;
            box.y = cy - 0.5f * h;
            box.z = cx + 0.5f * w;
            box.w = cy + 0.5f * h;
        } else {
            box = make_float4(0.0f, 0.0f, 0.0f, 0.0f);
        }
        reinterpret_cast<float4*>(out)[an] = box;
        out[(size_t)kB * kNBox * 4 + an] = (float)cls;
        out[(size_t)kB * kNBox * 5 + an] = valid ? 1.0f : 0.0f;
    }
}

extern "C" void kernel_launch(void* const* d_in, const int* in_sizes, int n_in,
                              void* d_out, int out_size, void* d_ws, size_t ws_size,
                              hipStream_t stream) {
    const float* offsets = (const float*)d_in[0];
    const float* conf    = (const float*)d_in[1];
    const float* dboxes  = (const float*)d_in[2];
    float* out = (float*)d_out;

    dim3 grid((kNBox + kChunk - 1) / kChunk, kB);  // 35 x 128 = 4480 blocks
    ssd_decode_kernel<<<grid, kChunk, 0, stream>>>(offsets, conf, dboxes, out);
}